// Round 1
// baseline (26268.924 us; speedup 1.0000x reference)
//
#include <hip/hip_runtime.h>

typedef _Float16 f16;
typedef _Float16 half8 __attribute__((ext_vector_type(8)));
typedef float f32x4 __attribute__((ext_vector_type(4)));

#define B_  64
#define T_  512
#define V_  32000
#define E_  300
#define EP  320      // E padded to multiple of 32 for MFMA K
#define U_  1024
#define G3  3072     // 3*U

// ---- workspace layout (bytes) ----
#define OFF_XE   0ull
#define OFF_W1T  (OFF_XE  + (size_t)B_*T_*EP*2)      // xe fp16 [32768][320]
#define OFF_W2F  (OFF_W1T + (size_t)G3*EP*2)         // w1^T fp16 [3072][320]
#define OFF_XP   (OFF_W2F + (size_t)U_*G3*2)         // w2 frag-shuffled fp16
#define OFF_H16  (OFF_XP  + (size_t)T_*B_*G3*2)      // xp fp16 [t][b][3072]
#define OFF_CTR  (OFF_H16 + 2ull*B_*U_*2)            // h fp16 double buffer
// total ≈ 230.8 MB

// ---------------- setup kernels ----------------

// gather + fp32->fp16 + K-pad: xe[bt][0..319]
__global__ void k_gather(const int* __restrict__ x, const float* __restrict__ emb,
                         f16* __restrict__ xe) {
    int row  = blockIdx.x * 4 + (threadIdx.x >> 6);
    int lane = threadIdx.x & 63;
    int tok  = x[row];
    const float* er = emb + (size_t)tok * E_;
    f16* xr = xe + (size_t)row * EP;
#pragma unroll
    for (int e = lane; e < EP; e += 64) {
        float v = (e < E_) ? er[e] : 0.f;
        xr[e] = (f16)v;
    }
}

// kernel (E,3U) -> transposed padded fp16 w1t[n][k]
__global__ void k_w1t(const float* __restrict__ w1, f16* __restrict__ w1t) {
    int n = blockIdx.x;        // 0..3071
    int k = threadIdx.x;       // 0..319 (block = 320 threads)
    float v = (k < E_) ? w1[(size_t)k * G3 + n] : 0.f;
    w1t[(size_t)n * EP + k] = (f16)v;
}

// recurrent_kernel (U,3U) -> MFMA B-fragment order fp16:
// w2f[((nt*32+kt)*64+lane)*8 + j] = W2[kt*32+(lane>>4)*8+j][nt*16+(lane&15)]
__global__ void k_w2f(const float* __restrict__ w2, f16* __restrict__ w2f) {
    int g    = blockIdx.x * 256 + threadIdx.x;   // 192*32*64 = 393216 total
    int lane = g & 63;
    int kt   = (g >> 6) & 31;
    int nt   = g >> 11;                          // 0..191
    int krow = kt * 32 + (lane >> 4) * 8;
    int n    = nt * 16 + (lane & 15);
    f16* dst = w2f + ((size_t)(nt * 32 + kt) * 64 + lane) * 8;
#pragma unroll
    for (int j = 0; j < 8; ++j)
        dst[j] = (f16)w2[(size_t)(krow + j) * G3 + n];
}

// hidden fp32 -> fp16 broadcast buffer 0
__global__ void k_hinit(const float* __restrict__ h0, f16* __restrict__ h16) {
    int i = blockIdx.x * 256 + threadIdx.x;      // 65536
    h16[i] = (f16)h0[i];
}

// ---------------- input projection GEMM ----------------
// xp[t][b][n] = xe[bt] @ w1 + bias0,  M=32768 N=3072 K=320, fp16 in/out fp32 acc
__global__ __launch_bounds__(256) void k_xp(const f16* __restrict__ xe,
                                            const f16* __restrict__ w1t,
                                            const float* __restrict__ bias0,
                                            f16* __restrict__ xp) {
    __shared__ __align__(16) f16 As[128 * 32];   // [row][k]
    __shared__ __align__(16) f16 Bs[128 * 32];   // [n][k]
    const int tid  = threadIdx.x;
    const int lane = tid & 63;
    const int w    = tid >> 6;
    const int wm   = w >> 1, wn = w & 1;
    const int n0   = blockIdx.x * 128;           // 24 n-tiles
    const int m0   = blockIdx.y * 128;           // 256 m-tiles

    f32x4 acc[4][4];
    const f32x4 z4 = {0.f, 0.f, 0.f, 0.f};
#pragma unroll
    for (int i = 0; i < 4; ++i)
#pragma unroll
        for (int j = 0; j < 4; ++j) acc[i][j] = z4;

    for (int kk = 0; kk < EP / 32; ++kk) {
        int k0 = kk * 32;
        __syncthreads();
#pragma unroll
        for (int c = 0; c < 2; ++c) {
            int t2 = tid + 256 * c;
            int row = t2 >> 2, kq = t2 & 3;
            ((half8*)As)[t2] = *(const half8*)(xe  + (size_t)(m0 + row) * EP + k0 + kq * 8);
            ((half8*)Bs)[t2] = *(const half8*)(w1t + (size_t)(n0 + row) * EP + k0 + kq * 8);
        }
        __syncthreads();
        half8 a[4], b[4];
#pragma unroll
        for (int i = 0; i < 4; ++i) {
            a[i] = ((half8*)As)[(wm * 64 + i * 16 + (lane & 15)) * 4 + (lane >> 4)];
            b[i] = ((half8*)Bs)[(wn * 64 + i * 16 + (lane & 15)) * 4 + (lane >> 4)];
        }
#pragma unroll
        for (int i = 0; i < 4; ++i)
#pragma unroll
            for (int j = 0; j < 4; ++j)
                acc[i][j] = __builtin_amdgcn_mfma_f32_16x16x32_f16(a[i], b[j], acc[i][j], 0, 0, 0);
    }

    float bv[4];
#pragma unroll
    for (int j = 0; j < 4; ++j) bv[j] = bias0[n0 + wn * 64 + j * 16 + (lane & 15)];
#pragma unroll
    for (int i = 0; i < 4; ++i)
#pragma unroll
        for (int j = 0; j < 4; ++j)
#pragma unroll
            for (int e = 0; e < 4; ++e) {
                int rl  = wm * 64 + i * 16 + (lane >> 4) * 4 + e;
                int bt  = m0 + rl;
                int tt  = bt & (T_ - 1);
                int bb  = bt >> 9;
                int col = n0 + wn * 64 + j * 16 + (lane & 15);
                xp[((size_t)tt * B_ + bb) * G3 + col] = (f16)(acc[i][j][e] + bv[j]);
            }
}

// ---------------- persistent GRU recurrence ----------------
// 256 WGs: ut = blk>>2 (16 u each), rw = blk&3 (16 batch rows each).
// Waves K-split (256 each); W2 slice resident in VGPRs; h broadcast fp16 via L2.
__global__ __launch_bounds__(256, 1) void k_rec(const f16* __restrict__ xp,
                                                const f16* __restrict__ w2f,
                                                const float* __restrict__ bias1,
                                                const float* __restrict__ h0,
                                                f16* __restrict__ h16,
                                                float* __restrict__ out,
                                                unsigned* __restrict__ ctr) {
    const int tid  = threadIdx.x;
    const int lane = tid & 63;
    const int wave = tid >> 6;
    const int ut   = blockIdx.x >> 2;
    const int rw   = blockIdx.x & 3;

    __shared__ __align__(16) float red[4][3][64][4];   // 12 KB wave partials

    // resident B fragments: 3 gates x 8 k-tiles (per-wave K chunk of 256)
    half8 bw[3][8];
#pragma unroll
    for (int g = 0; g < 3; ++g) {
        int nt = g * 64 + ut;
#pragma unroll
        for (int k8 = 0; k8 < 8; ++k8) {
            int kt = wave * 8 + k8;
            bw[g][k8] = *(const half8*)(w2f + ((size_t)(nt * 32 + kt) * 64 + lane) * 8);
        }
    }

    const int row_l = tid >> 4;             // 0..15
    const int colu  = tid & 15;
    const int row   = rw * 16 + row_l;      // batch index
    const int ug    = ut * 16 + colu;       // hidden unit
    float h = h0[row * U_ + ug];            // fp32 state lives in a register
    const float bz = bias1[ug], br = bias1[U_ + ug], bh = bias1[2 * U_ + ug];
    const int lsrc = (row_l >> 2) * 16 + colu;
    const int ei   = row_l & 3;
    const int arow = rw * 16 + (lane & 15);
    const int kb   = wave * 256 + (lane >> 4) * 8;
    const f32x4 z4 = {0.f, 0.f, 0.f, 0.f};

#pragma unroll 1
    for (int t = 0; t < T_; ++t) {
        const f16* hc = h16 + (size_t)(t & 1) * (B_ * U_);
        f16*       hn = h16 + (size_t)((t + 1) & 1) * (B_ * U_);

        half8 af[8];
#pragma unroll
        for (int k8 = 0; k8 < 8; ++k8)
            af[k8] = *(const half8*)(hc + (size_t)arow * U_ + kb + k8 * 32);

        f32x4 acc[3] = {z4, z4, z4};
#pragma unroll
        for (int k8 = 0; k8 < 8; ++k8)
#pragma unroll
            for (int g = 0; g < 3; ++g)
                acc[g] = __builtin_amdgcn_mfma_f32_16x16x32_f16(af[k8], bw[g][k8], acc[g], 0, 0, 0);

#pragma unroll
        for (int g = 0; g < 3; ++g)
            *(f32x4*)&red[wave][g][lane][0] = acc[g];
        __syncthreads();

        float sz = red[0][0][lsrc][ei] + red[1][0][lsrc][ei] + red[2][0][lsrc][ei] + red[3][0][lsrc][ei];
        float sr = red[0][1][lsrc][ei] + red[1][1][lsrc][ei] + red[2][1][lsrc][ei] + red[3][1][lsrc][ei];
        float sh = red[0][2][lsrc][ei] + red[1][2][lsrc][ei] + red[2][2][lsrc][ei] + red[3][2][lsrc][ei];

        const f16* xpt = xp + ((size_t)t * B_ + row) * G3;
        float xz = (float)xpt[ug];
        float xr = (float)xpt[U_ + ug];
        float xh = (float)xpt[2 * U_ + ug];

        float zg = 1.f / (1.f + expf(-(xz + sz + bz)));
        float rg = 1.f / (1.f + expf(-(xr + sr + br)));
        float hh = tanhf(xh + rg * (sh + bh));
        h = zg * h + (1.f - zg) * hh;

        out[((size_t)row * T_ + t) * U_ + ug] = h;
        hn[row * U_ + ug] = (f16)h;

        // --- grid barrier (per-step counter, device scope) ---
        __threadfence();             // make h16/out stores visible agent-wide
        __syncthreads();             // also protects `red` reuse
        if (tid == 0) {
            __hip_atomic_fetch_add(&ctr[t], 1u, __ATOMIC_RELEASE, __HIP_MEMORY_SCOPE_AGENT);
            while (__hip_atomic_load(&ctr[t], __ATOMIC_ACQUIRE, __HIP_MEMORY_SCOPE_AGENT) < 256u)
                __builtin_amdgcn_s_sleep(2);
        }
        __syncthreads();
        __threadfence();             // acquire: invalidate stale h16 in L1/L2
    }
    // final state chunk
    out[(size_t)B_ * T_ * U_ + (size_t)row * U_ + ug] = h;
}

// ---------------- host ----------------
extern "C" void kernel_launch(void* const* d_in, const int* in_sizes, int n_in,
                              void* d_out, int out_size, void* d_ws, size_t ws_size,
                              hipStream_t stream) {
    const int*   x    = (const int*)d_in[0];
    const float* h0   = (const float*)d_in[1];
    const float* emb  = (const float*)d_in[2];
    const float* w1   = (const float*)d_in[3];
    const float* w2   = (const float*)d_in[4];
    const float* bias = (const float*)d_in[5];
    float* out = (float*)d_out;
    char*  ws  = (char*)d_ws;

    f16*      xe   = (f16*)(ws + OFF_XE);
    f16*      w1t  = (f16*)(ws + OFF_W1T);
    f16*      w2f  = (f16*)(ws + OFF_W2F);
    f16*      xp   = (f16*)(ws + OFF_XP);
    f16*      h16  = (f16*)(ws + OFF_H16);
    unsigned* ctr  = (unsigned*)(ws + OFF_CTR);

    hipMemsetAsync(ctr, 0, T_ * sizeof(unsigned), stream);
    k_gather<<<B_ * T_ / 4, 256, 0, stream>>>(x, emb, xe);
    k_w1t<<<G3, EP, 0, stream>>>(w1, w1t);
    k_w2f<<<(192 * 32 * 64) / 256, 256, 0, stream>>>(w2, w2f);
    k_hinit<<<B_ * U_ / 256, 256, 0, stream>>>(h0, h16);
    k_xp<<<dim3(G3 / 128, B_ * T_ / 128), 256, 0, stream>>>(xe, w1t, bias, xp);

    const f16*   xp_c   = xp;
    const f16*   w2f_c  = w2f;
    const float* bias1  = bias + G3;
    void* args[] = {(void*)&xp_c, (void*)&w2f_c, (void*)&bias1, (void*)&h0,
                    (void*)&h16, (void*)&out, (void*)&ctr};
    if (hipLaunchCooperativeKernel((const void*)k_rec, dim3(256), dim3(256),
                                   args, 0, stream) != hipSuccess) {
        // fallback: 256 blocks / 256 CUs are co-resident de-facto
        k_rec<<<256, 256, 0, stream>>>(xp_c, w2f_c, bias1, h0, h16, out, ctr);
    }
}

// Round 2
// 2513.504 us; speedup vs baseline: 10.4511x; 10.4511x over previous
//
#include <hip/hip_runtime.h>

typedef _Float16 f16;
typedef _Float16 half8 __attribute__((ext_vector_type(8)));
typedef float f32x4 __attribute__((ext_vector_type(4)));

#define B_  64
#define T_  512
#define V_  32000
#define E_  300
#define EP  320      // E padded to multiple of 32 for MFMA K
#define U_  1024
#define G3  3072     // 3*U

// ---- workspace layout (bytes) ----
#define OFF_XE   0ull
#define OFF_W1T  (OFF_XE  + (size_t)B_*T_*EP*2)      // xe fp16 [32768][320]
#define OFF_W2F  (OFF_W1T + (size_t)G3*EP*2)         // w1^T fp16 [3072][320]
#define OFF_XP   (OFF_W2F + (size_t)U_*G3*2)         // w2 frag-shuffled fp16
#define OFF_CTR  (OFF_XP  + (size_t)T_*B_*G3*2)      // xp fp16 [t][b][3072]
// total ≈ 208 MB + 8 KB counters

// ---------------- setup kernels ----------------

__global__ void k_gather(const int* __restrict__ x, const float* __restrict__ emb,
                         f16* __restrict__ xe) {
    int row  = blockIdx.x * 4 + (threadIdx.x >> 6);
    int lane = threadIdx.x & 63;
    int tok  = x[row];
    const float* er = emb + (size_t)tok * E_;
    f16* xr = xe + (size_t)row * EP;
#pragma unroll
    for (int e = lane; e < EP; e += 64) {
        float v = (e < E_) ? er[e] : 0.f;
        xr[e] = (f16)v;
    }
}

__global__ void k_w1t(const float* __restrict__ w1, f16* __restrict__ w1t) {
    int n = blockIdx.x;        // 0..3071
    int k = threadIdx.x;       // 0..319
    float v = (k < E_) ? w1[(size_t)k * G3 + n] : 0.f;
    w1t[(size_t)n * EP + k] = (f16)v;
}

// recurrent_kernel (U,3U) -> MFMA B-fragment order fp16
__global__ void k_w2f(const float* __restrict__ w2, f16* __restrict__ w2f) {
    int g    = blockIdx.x * 256 + threadIdx.x;
    int lane = g & 63;
    int kt   = (g >> 6) & 31;
    int nt   = g >> 11;                          // 0..191
    int krow = kt * 32 + (lane >> 4) * 8;
    int n    = nt * 16 + (lane & 15);
    f16* dst = w2f + ((size_t)(nt * 32 + kt) * 64 + lane) * 8;
#pragma unroll
    for (int j = 0; j < 8; ++j)
        dst[j] = (f16)w2[(size_t)(krow + j) * G3 + n];
}

// ---------------- input projection GEMM ----------------
__global__ __launch_bounds__(256) void k_xp(const f16* __restrict__ xe,
                                            const f16* __restrict__ w1t,
                                            const float* __restrict__ bias0,
                                            f16* __restrict__ xp) {
    __shared__ __align__(16) f16 As[128 * 32];
    __shared__ __align__(16) f16 Bs[128 * 32];
    const int tid  = threadIdx.x;
    const int lane = tid & 63;
    const int w    = tid >> 6;
    const int wm   = w >> 1, wn = w & 1;
    const int n0   = blockIdx.x * 128;
    const int m0   = blockIdx.y * 128;

    f32x4 acc[4][4];
    const f32x4 z4 = {0.f, 0.f, 0.f, 0.f};
#pragma unroll
    for (int i = 0; i < 4; ++i)
#pragma unroll
        for (int j = 0; j < 4; ++j) acc[i][j] = z4;

    for (int kk = 0; kk < EP / 32; ++kk) {
        int k0 = kk * 32;
        __syncthreads();
#pragma unroll
        for (int c = 0; c < 2; ++c) {
            int t2 = tid + 256 * c;
            int row = t2 >> 2, kq = t2 & 3;
            ((half8*)As)[t2] = *(const half8*)(xe  + (size_t)(m0 + row) * EP + k0 + kq * 8);
            ((half8*)Bs)[t2] = *(const half8*)(w1t + (size_t)(n0 + row) * EP + k0 + kq * 8);
        }
        __syncthreads();
        half8 a[4], b[4];
#pragma unroll
        for (int i = 0; i < 4; ++i) {
            a[i] = ((half8*)As)[(wm * 64 + i * 16 + (lane & 15)) * 4 + (lane >> 4)];
            b[i] = ((half8*)Bs)[(wn * 64 + i * 16 + (lane & 15)) * 4 + (lane >> 4)];
        }
#pragma unroll
        for (int i = 0; i < 4; ++i)
#pragma unroll
            for (int j = 0; j < 4; ++j)
                acc[i][j] = __builtin_amdgcn_mfma_f32_16x16x32_f16(a[i], b[j], acc[i][j], 0, 0, 0);
    }

    float bv[4];
#pragma unroll
    for (int j = 0; j < 4; ++j) bv[j] = bias0[n0 + wn * 64 + j * 16 + (lane & 15)];
#pragma unroll
    for (int i = 0; i < 4; ++i)
#pragma unroll
        for (int j = 0; j < 4; ++j)
#pragma unroll
            for (int e = 0; e < 4; ++e) {
                int rl  = wm * 64 + i * 16 + (lane >> 4) * 4 + e;
                int bt  = m0 + rl;
                int tt  = bt & (T_ - 1);
                int bb  = bt >> 9;
                int col = n0 + wn * 64 + j * 16 + (lane & 15);
                xp[((size_t)tt * B_ + bb) * G3 + col] = (f16)(acc[i][j][e] + bv[j]);
            }
}

// ---------------- persistent GRU recurrence ----------------
// 256 WGs: ut = blk>>2 (16 u), rw = blk&3 (16 batch rows). 4 independent
// barrier groups of 64 blocks (batch groups never interact).
// h exchanged THROUGH `out` (fp32, [b][t][u]): written once with sc1
// (agent-relaxed atomic store -> write-through to coherent point), read once
// with plain vector loads after the group barrier. No fences, no L2
// writeback/invalidate anywhere in the step loop.
__global__ __launch_bounds__(256, 1) void k_rec(const f16* __restrict__ xp,
                                                const f16* __restrict__ w2f,
                                                const float* __restrict__ bias1,
                                                const float* __restrict__ h0,
                                                float* __restrict__ out,
                                                unsigned* __restrict__ ctr) {
    const int tid  = threadIdx.x;
    const int lane = tid & 63;
    const int wave = tid >> 6;
    const int ut   = blockIdx.x >> 2;
    const int rw   = blockIdx.x & 3;

    __shared__ __align__(16) float red[4][3][64][4];

    // resident B fragments: 3 gates x 8 k-tiles (per-wave K chunk of 256)
    half8 bw[3][8];
#pragma unroll
    for (int g = 0; g < 3; ++g) {
        int nt = g * 64 + ut;
#pragma unroll
        for (int k8 = 0; k8 < 8; ++k8) {
            int kt = wave * 8 + k8;
            bw[g][k8] = *(const half8*)(w2f + ((size_t)(nt * 32 + kt) * 64 + lane) * 8);
        }
    }
    // pin the 96 weight VGPRs: opaque asm so the compiler cannot sink the
    // loads into the t-loop (R1: VGPR_Count=72 proved they were re-loaded)
    {
        f32x4* p = (f32x4*)&bw[0][0];
#pragma unroll
        for (int i = 0; i < 24; ++i)
            asm volatile("" : "+v"(p[i][0]), "+v"(p[i][1]), "+v"(p[i][2]), "+v"(p[i][3]));
    }

    const int row_l = tid >> 4;             // 0..15
    const int colu  = tid & 15;
    const int row   = rw * 16 + row_l;      // batch index
    const int ug    = ut * 16 + colu;       // hidden unit
    float h = h0[row * U_ + ug];
    const float bz = bias1[ug], br = bias1[U_ + ug], bh = bias1[2 * U_ + ug];
    const int lsrc = (row_l >> 2) * 16 + colu;
    const int ei   = row_l & 3;
    const int rowA = rw * 16 + (lane & 15); // A-fragment batch row for this lane
    const int kb   = wave * 256 + (lane >> 4) * 8;
    const f32x4 z4 = {0.f, 0.f, 0.f, 0.f};
    unsigned* myctr = ctr + rw;             // ctr[t*4 + rw]

#pragma unroll 1
    for (int t = 0; t < T_; ++t) {
        // h_{t-1} source: h0 for t=0, else the out trajectory (fp32)
        const float* hc = (t == 0) ? (h0 + (size_t)rowA * U_)
                                   : (out + ((size_t)rowA * T_ + (t - 1)) * U_);
        half8 af[8];
#pragma unroll
        for (int k8 = 0; k8 < 8; ++k8) {
            f32x4 u0 = *(const f32x4*)(hc + kb + k8 * 32);
            f32x4 u1 = *(const f32x4*)(hc + kb + k8 * 32 + 4);
#pragma unroll
            for (int j = 0; j < 4; ++j) {
                af[k8][j]     = (f16)u0[j];
                af[k8][4 + j] = (f16)u1[j];
            }
        }

        // xp loads early to overlap latency with MFMA
        const f16* xpt = xp + ((size_t)t * B_ + row) * G3;
        float xz = (float)xpt[ug];
        float xr = (float)xpt[U_ + ug];
        float xh = (float)xpt[2 * U_ + ug];

        f32x4 acc[3] = {z4, z4, z4};
#pragma unroll
        for (int k8 = 0; k8 < 8; ++k8)
#pragma unroll
            for (int g = 0; g < 3; ++g)
                acc[g] = __builtin_amdgcn_mfma_f32_16x16x32_f16(af[k8], bw[g][k8], acc[g], 0, 0, 0);

#pragma unroll
        for (int g = 0; g < 3; ++g)
            *(f32x4*)&red[wave][g][lane][0] = acc[g];
        __syncthreads();

        float sz = red[0][0][lsrc][ei] + red[1][0][lsrc][ei] + red[2][0][lsrc][ei] + red[3][0][lsrc][ei];
        float sr = red[0][1][lsrc][ei] + red[1][1][lsrc][ei] + red[2][1][lsrc][ei] + red[3][1][lsrc][ei];
        float sh = red[0][2][lsrc][ei] + red[1][2][lsrc][ei] + red[2][2][lsrc][ei] + red[3][2][lsrc][ei];

        float zg = 1.f / (1.f + expf(-(xz + sz + bz)));
        float rg = 1.f / (1.f + expf(-(xr + sr + br)));
        float hh = tanhf(xh + rg * (sh + bh));
        h = zg * h + (1.f - zg) * hh;

        // publish h_t: write-through to coherent point (sc1), no fence needed
        __hip_atomic_store(out + ((size_t)row * T_ + t) * U_ + ug, h,
                           __ATOMIC_RELAXED, __HIP_MEMORY_SCOPE_AGENT);

        // __syncthreads drains vmcnt(0) per-thread before s_barrier, so once
        // all threads pass, every lane's sc1 store is at the coherent point.
        __syncthreads();
        if (tid == 0) {
            __hip_atomic_fetch_add(myctr + (size_t)t * 4, 1u,
                                   __ATOMIC_RELAXED, __HIP_MEMORY_SCOPE_AGENT);
            while (__hip_atomic_load(myctr + (size_t)t * 4,
                                     __ATOMIC_RELAXED, __HIP_MEMORY_SCOPE_AGENT) < 64u)
                __builtin_amdgcn_s_sleep(2);
        }
        __syncthreads();
    }
    out[(size_t)B_ * T_ * U_ + (size_t)row * U_ + ug] = h;
}

// ---------------- host ----------------
extern "C" void kernel_launch(void* const* d_in, const int* in_sizes, int n_in,
                              void* d_out, int out_size, void* d_ws, size_t ws_size,
                              hipStream_t stream) {
    const int*   x    = (const int*)d_in[0];
    const float* h0   = (const float*)d_in[1];
    const float* emb  = (const float*)d_in[2];
    const float* w1   = (const float*)d_in[3];
    const float* w2   = (const float*)d_in[4];
    const float* bias = (const float*)d_in[5];
    float* out = (float*)d_out;
    char*  ws  = (char*)d_ws;

    f16*      xe   = (f16*)(ws + OFF_XE);
    f16*      w1t  = (f16*)(ws + OFF_W1T);
    f16*      w2f  = (f16*)(ws + OFF_W2F);
    f16*      xp   = (f16*)(ws + OFF_XP);
    unsigned* ctr  = (unsigned*)(ws + OFF_CTR);

    hipMemsetAsync(ctr, 0, T_ * 4 * sizeof(unsigned), stream);
    k_gather<<<B_ * T_ / 4, 256, 0, stream>>>(x, emb, xe);
    k_w1t<<<G3, EP, 0, stream>>>(w1, w1t);
    k_w2f<<<(192 * 32 * 64) / 256, 256, 0, stream>>>(w2, w2f);
    k_xp<<<dim3(G3 / 128, B_ * T_ / 128), 256, 0, stream>>>(xe, w1t, bias, xp);

    const f16*   xp_c   = xp;
    const f16*   w2f_c  = w2f;
    const float* bias1  = bias + G3;
    void* args[] = {(void*)&xp_c, (void*)&w2f_c, (void*)&bias1, (void*)&h0,
                    (void*)&out, (void*)&ctr};
    if (hipLaunchCooperativeKernel((const void*)k_rec, dim3(256), dim3(256),
                                   args, 0, stream) != hipSuccess) {
        k_rec<<<256, 256, 0, stream>>>(xp_c, w2f_c, bias1, h0, out, ctr);
    }
}

// Round 3
// 2124.069 us; speedup vs baseline: 12.3673x; 1.1833x over previous
//
#include <hip/hip_runtime.h>

typedef _Float16 f16;
typedef _Float16 half8 __attribute__((ext_vector_type(8)));
typedef float f32x4 __attribute__((ext_vector_type(4)));
typedef unsigned long long u64;

#define B_  64
#define T_  512
#define V_  32000
#define E_  300
#define EP  320      // E padded to multiple of 32 for MFMA K
#define U_  1024
#define G3  3072     // 3*U

// ---- workspace layout (bytes) ----
// XE region is time-shared: k_gather/k_xp use it first, then hx/ctr live in it.
#define OFF_XE   0ull
#define OFF_HX   OFF_XE                               // hx[2][64][1024] fp16 (256 KB)
#define OFF_CTR2 (OFF_XE + 2ull*B_*U_*2)              // ctr[4][2048] (32 KB)
#define OFF_W1T  (OFF_XE  + (size_t)B_*T_*EP*2)       // xe fp16 [32768][320]
#define OFF_W2F  (OFF_W1T + (size_t)G3*EP*2)
#define OFF_XP   (OFF_W2F + (size_t)U_*G3*2)
// total ≈ 230.6 MB (same footprint as R2)

__device__ __forceinline__ void barrier_lds() {
    // __syncthreads() drains vmcnt(0) too, killing in-flight prefetches.
    // For LDS-only dependencies, lgkmcnt(0) suffices.
    asm volatile("s_waitcnt lgkmcnt(0)\n\ts_barrier" ::: "memory");
}

// ---------------- setup kernels ----------------

__global__ void k_gather(const int* __restrict__ x, const float* __restrict__ emb,
                         f16* __restrict__ xe) {
    int row  = blockIdx.x * 4 + (threadIdx.x >> 6);
    int lane = threadIdx.x & 63;
    int tok  = x[row];
    const float* er = emb + (size_t)tok * E_;
    f16* xr = xe + (size_t)row * EP;
#pragma unroll
    for (int e = lane; e < EP; e += 64) {
        float v = (e < E_) ? er[e] : 0.f;
        xr[e] = (f16)v;
    }
}

__global__ void k_w1t(const float* __restrict__ w1, f16* __restrict__ w1t) {
    int n = blockIdx.x;
    int k = threadIdx.x;
    float v = (k < E_) ? w1[(size_t)k * G3 + n] : 0.f;
    w1t[(size_t)n * EP + k] = (f16)v;
}

__global__ void k_w2f(const float* __restrict__ w2, f16* __restrict__ w2f) {
    int g    = blockIdx.x * 256 + threadIdx.x;
    int lane = g & 63;
    int kt   = (g >> 6) & 31;
    int nt   = g >> 11;
    int krow = kt * 32 + (lane >> 4) * 8;
    int n    = nt * 16 + (lane & 15);
    f16* dst = w2f + ((size_t)(nt * 32 + kt) * 64 + lane) * 8;
#pragma unroll
    for (int j = 0; j < 8; ++j)
        dst[j] = (f16)w2[(size_t)(krow + j) * G3 + n];
}

// h0 fp32 -> hx[0] fp16, published at agent scope
__global__ void k_hinit(const float* __restrict__ h0, f16* __restrict__ hx) {
    int i = blockIdx.x * 256 + threadIdx.x;        // 0..32767 (dword pairs)
    f16 a = (f16)h0[2 * i], b = (f16)h0[2 * i + 1];
    unsigned lo = *(unsigned short*)&a, hi = *(unsigned short*)&b;
    __hip_atomic_store((unsigned*)hx + i, lo | (hi << 16),
                       __ATOMIC_RELAXED, __HIP_MEMORY_SCOPE_AGENT);
}

// ---------------- input projection GEMM ----------------
__global__ __launch_bounds__(256) void k_xp(const f16* __restrict__ xe,
                                            const f16* __restrict__ w1t,
                                            const float* __restrict__ bias0,
                                            f16* __restrict__ xp) {
    __shared__ __align__(16) f16 As[128 * 32];
    __shared__ __align__(16) f16 Bs[128 * 32];
    const int tid  = threadIdx.x;
    const int lane = tid & 63;
    const int w    = tid >> 6;
    const int wm   = w >> 1, wn = w & 1;
    const int n0   = blockIdx.x * 128;
    const int m0   = blockIdx.y * 128;

    f32x4 acc[4][4];
    const f32x4 z4 = {0.f, 0.f, 0.f, 0.f};
#pragma unroll
    for (int i = 0; i < 4; ++i)
#pragma unroll
        for (int j = 0; j < 4; ++j) acc[i][j] = z4;

    for (int kk = 0; kk < EP / 32; ++kk) {
        int k0 = kk * 32;
        __syncthreads();
#pragma unroll
        for (int c = 0; c < 2; ++c) {
            int t2 = tid + 256 * c;
            int row = t2 >> 2, kq = t2 & 3;
            ((half8*)As)[t2] = *(const half8*)(xe  + (size_t)(m0 + row) * EP + k0 + kq * 8);
            ((half8*)Bs)[t2] = *(const half8*)(w1t + (size_t)(n0 + row) * EP + k0 + kq * 8);
        }
        __syncthreads();
        half8 a[4], b[4];
#pragma unroll
        for (int i = 0; i < 4; ++i) {
            a[i] = ((half8*)As)[(wm * 64 + i * 16 + (lane & 15)) * 4 + (lane >> 4)];
            b[i] = ((half8*)Bs)[(wn * 64 + i * 16 + (lane & 15)) * 4 + (lane >> 4)];
        }
#pragma unroll
        for (int i = 0; i < 4; ++i)
#pragma unroll
            for (int j = 0; j < 4; ++j)
                acc[i][j] = __builtin_amdgcn_mfma_f32_16x16x32_f16(a[i], b[j], acc[i][j], 0, 0, 0);
    }

    float bv[4];
#pragma unroll
    for (int j = 0; j < 4; ++j) bv[j] = bias0[n0 + wn * 64 + j * 16 + (lane & 15)];
#pragma unroll
    for (int i = 0; i < 4; ++i)
#pragma unroll
        for (int j = 0; j < 4; ++j)
#pragma unroll
            for (int e = 0; e < 4; ++e) {
                int rl  = wm * 64 + i * 16 + (lane >> 4) * 4 + e;
                int bt  = m0 + rl;
                int tt  = bt & (T_ - 1);
                int bb  = bt >> 9;
                int col = n0 + wn * 64 + j * 16 + (lane & 15);
                xp[((size_t)tt * B_ + bb) * G3 + col] = (f16)(acc[i][j][e] + bv[j]);
            }
}

// ---------------- persistent GRU recurrence ----------------
// 128 blocks x 512 threads. blk: rw = blk&3 (16 batch rows), ut2 = blk>>2
// (32 hidden units). Waves: uw = wave>>2 (u-tile), kw = wave&3 (K chunk 256).
// Per step: stage group h (fp16, 32 KB) L3->LDS once, reuse across both
// u-tiles; MFMA; LDS K-reduce; epilogue; publish h fp16 + group barrier.
__global__ __launch_bounds__(512, 1) void k_rec(const f16* __restrict__ xp,
                                                const f16* __restrict__ w2f,
                                                const float* __restrict__ bias1,
                                                const float* __restrict__ h0,
                                                f16* __restrict__ hx,
                                                float* __restrict__ out,
                                                unsigned* __restrict__ ctr) {
    const int tid  = threadIdx.x;
    const int lane = tid & 63;
    const int wave = tid >> 6;          // 0..7
    const int uw   = wave >> 2;         // 0..1
    const int kw   = wave & 3;          // 0..3
    const int rw   = blockIdx.x & 3;
    const int ut2  = blockIdx.x >> 2;   // 0..31
    const int ut16 = ut2 * 2 + uw;      // 16-u tile id 0..63

    __shared__ __align__(16) f16   hs[16 * 1032];       // 33 KB staged h (+pad)
    __shared__ __align__(16) float red[8][3][64][4];    // 24 KB K-partials

    // resident weights: 3 gates x 8 k-tiles for this wave's (u-tile, K-chunk)
    half8 bw[3][8];
#pragma unroll
    for (int g = 0; g < 3; ++g) {
        int nt = g * 64 + ut16;
#pragma unroll
        for (int k8 = 0; k8 < 8; ++k8) {
            int kt = kw * 8 + k8;
            bw[g][k8] = *(const half8*)(w2f + ((size_t)(nt * 32 + kt) * 64 + lane) * 8);
        }
    }
    {   // pin weights in registers so loads can't sink into the t-loop
        f32x4* p = (f32x4*)&bw[0][0];
#pragma unroll
        for (int i = 0; i < 24; ++i)
            asm volatile("" : "+v"(p[i][0]), "+v"(p[i][1]), "+v"(p[i][2]), "+v"(p[i][3]));
    }

    const int row  = tid >> 5;          // 0..15
    const int u32  = tid & 31;          // 0..31
    const int rowg = rw * 16 + row;     // global batch row
    const int ug   = ut2 * 32 + u32;    // hidden unit 0..1023
    float h = h0[rowg * U_ + ug];       // fp32 state in register
    const float bz = bias1[ug], br = bias1[U_ + ug], bh = bias1[2 * U_ + ug];
    const int lsrc = (row >> 2) * 16 + (u32 & 15);
    const int ei   = row & 3;
    const int uwq  = u32 >> 4;
    const f32x4 z4 = {0.f, 0.f, 0.f, 0.f};
    unsigned* myctr = ctr + rw * 2048;  // per-group private page

    // stage-load geometry: this thread moves 64 B of the group's h slice
    const size_t gsl = (size_t)(rw * 16 + row) * U_ + u32 * 32;   // halves
    u64* lds_dst = (u64*)((char*)hs + row * 2064 + u32 * 64);
    const f16* hrow = hs + (lane & 15) * 1032 + kw * 256 + (lane >> 4) * 8;

    // xp prefetch for t=0
    const f16* xpb = xp + (size_t)rowg * G3 + ug;
    float xz = (float)xpb[0], xr = (float)xpb[(size_t)U_], xh = (float)xpb[(size_t)2 * U_];

#pragma unroll 1
    for (int t = 0; t < T_; ++t) {
        // ---- 1. stage hx[t&1] -> LDS (agent-scope loads, L2-safe) ----
        const u64* gs = (const u64*)(hx + (size_t)(t & 1) * (B_ * U_) + gsl);
        u64 v[8];
#pragma unroll
        for (int i = 0; i < 8; ++i)
            v[i] = __hip_atomic_load(gs + i, __ATOMIC_RELAXED, __HIP_MEMORY_SCOPE_AGENT);
#pragma unroll
        for (int i = 0; i < 8; ++i) lds_dst[i] = v[i];
        barrier_lds();

        // ---- 2. A fragments from LDS ----
        half8 af[8];
#pragma unroll
        for (int k8 = 0; k8 < 8; ++k8)
            af[k8] = *(const half8*)(hrow + k8 * 32);

        // ---- 3. prefetch xp for t+1 (hidden behind MFMA+reduce) ----
        int tn = (t < T_ - 1) ? t + 1 : t;
        const f16* xpn = xp + ((size_t)tn * B_ + rowg) * G3 + ug;
        float xzn = (float)xpn[0], xrn = (float)xpn[(size_t)U_], xhn = (float)xpn[(size_t)2 * U_];

        // ---- 4. MFMA ----
        f32x4 acc[3] = {z4, z4, z4};
#pragma unroll
        for (int k8 = 0; k8 < 8; ++k8)
#pragma unroll
            for (int g = 0; g < 3; ++g)
                acc[g] = __builtin_amdgcn_mfma_f32_16x16x32_f16(af[k8], bw[g][k8], acc[g], 0, 0, 0);

        // ---- 5. K-reduce via LDS ----
#pragma unroll
        for (int g = 0; g < 3; ++g)
            *(f32x4*)&red[wave][g][lane][0] = acc[g];
        barrier_lds();

        float sz = 0.f, sr = 0.f, sh = 0.f;
#pragma unroll
        for (int k2 = 0; k2 < 4; ++k2) {
            int w2 = uwq * 4 + k2;
            sz += red[w2][0][lsrc][ei];
            sr += red[w2][1][lsrc][ei];
            sh += red[w2][2][lsrc][ei];
        }

        // ---- 6. epilogue ----
        float zg = 1.f / (1.f + expf(-(xz + sz + bz)));
        float rg = 1.f / (1.f + expf(-(xr + sr + br)));
        float hh = tanhf(xh + rg * (sh + bh));
        h = zg * h + (1.f - zg) * hh;

        out[((size_t)rowg * T_ + t) * U_ + ug] = h;            // plain store

        f16 hf = (f16)h;
        unsigned my = *(unsigned short*)&hf;
        unsigned nb = __shfl_down(my, 1);
        if ((u32 & 1) == 0) {
            unsigned* dst = (unsigned*)(hx + (size_t)((t + 1) & 1) * (B_ * U_)
                                        + (size_t)rowg * U_ + ug);
            __hip_atomic_store(dst, my | (nb << 16),
                               __ATOMIC_RELAXED, __HIP_MEMORY_SCOPE_AGENT);
        }

        // ---- 7. group barrier (full drain: hx store must reach L3) ----
        __syncthreads();
        if (tid == 0) {
            __hip_atomic_fetch_add(myctr + t, 1u,
                                   __ATOMIC_RELAXED, __HIP_MEMORY_SCOPE_AGENT);
            while (__hip_atomic_load(myctr + t,
                                     __ATOMIC_RELAXED, __HIP_MEMORY_SCOPE_AGENT) < 32u)
                __builtin_amdgcn_s_sleep(1);
        }
        __syncthreads();

        xz = xzn; xr = xrn; xh = xhn;
    }
    out[(size_t)B_ * T_ * U_ + (size_t)rowg * U_ + ug] = h;
}

// ---------------- host ----------------
extern "C" void kernel_launch(void* const* d_in, const int* in_sizes, int n_in,
                              void* d_out, int out_size, void* d_ws, size_t ws_size,
                              hipStream_t stream) {
    const int*   x    = (const int*)d_in[0];
    const float* h0   = (const float*)d_in[1];
    const float* emb  = (const float*)d_in[2];
    const float* w1   = (const float*)d_in[3];
    const float* w2   = (const float*)d_in[4];
    const float* bias = (const float*)d_in[5];
    float* out = (float*)d_out;
    char*  ws  = (char*)d_ws;

    f16*      xe   = (f16*)(ws + OFF_XE);
    f16*      w1t  = (f16*)(ws + OFF_W1T);
    f16*      w2f  = (f16*)(ws + OFF_W2F);
    f16*      xp   = (f16*)(ws + OFF_XP);
    f16*      hx   = (f16*)(ws + OFF_HX);     // time-shared with xe (dead after k_xp)
    unsigned* ctr  = (unsigned*)(ws + OFF_CTR2);

    k_gather<<<B_ * T_ / 4, 256, 0, stream>>>(x, emb, xe);
    k_w1t<<<G3, EP, 0, stream>>>(w1, w1t);
    k_w2f<<<(192 * 32 * 64) / 256, 256, 0, stream>>>(w2, w2f);
    k_xp<<<dim3(G3 / 128, B_ * T_ / 128), 256, 0, stream>>>(xe, w1t, bias, xp);

    // xe region is dead now; hx/ctr live inside it
    hipMemsetAsync(ctr, 0, 4 * 2048 * sizeof(unsigned), stream);
    k_hinit<<<(B_ * U_ / 2) / 256, 256, 0, stream>>>(h0, hx);

    const f16*   xp_c   = xp;
    const f16*   w2f_c  = w2f;
    const float* bias1  = bias + G3;
    void* args[] = {(void*)&xp_c, (void*)&w2f_c, (void*)&bias1, (void*)&h0,
                    (void*)&hx, (void*)&out, (void*)&ctr};
    if (hipLaunchCooperativeKernel((const void*)k_rec, dim3(128), dim3(512),
                                   args, 0, stream) != hipSuccess) {
        k_rec<<<128, 512, 0, stream>>>(xp_c, w2f_c, bias1, h0, hx, out, ctr);
    }
}

// Round 4
// 1850.276 us; speedup vs baseline: 14.1973x; 1.1480x over previous
//
#include <hip/hip_runtime.h>

typedef _Float16 f16;
typedef _Float16 half8 __attribute__((ext_vector_type(8)));
typedef float f32x4 __attribute__((ext_vector_type(4)));
typedef unsigned long long u64;

#define B_  64
#define T_  512
#define V_  32000
#define E_  300
#define EP  320      // E padded to multiple of 32 for MFMA K
#define U_  1024
#define G3  3072     // 3*U

// ---- workspace layout (bytes) ----
// XE region is time-shared: k_gather/k_xp use it first, then hx/ctr live in it.
#define OFF_XE   0ull
#define OFF_HX   OFF_XE                               // hx[2][64][1024] fp16 (256 KB)
#define OFF_CTR2 (OFF_XE + 2ull*B_*U_*2)              // ctr[4][2048] (32 KB)
#define OFF_W1T  (OFF_XE  + (size_t)B_*T_*EP*2)       // xe fp16 [32768][320]
#define OFF_W2F  (OFF_W1T + (size_t)G3*EP*2)
#define OFF_XP   (OFF_W2F + (size_t)U_*G3*2)

__device__ __forceinline__ void barrier_lds() {
    // LDS-only dependency barrier: don't drain vmcnt (keeps prefetches alive)
    asm volatile("s_waitcnt lgkmcnt(0)\n\ts_barrier" ::: "memory");
}

// opaque 16B load: result is an asm output -> cannot be rematerialized, so
// the allocator must keep it in VGPRs for its whole live range
#define WLOAD(dst, src) \
    asm volatile("global_load_dwordx4 %0, %1, off" : "=v"(dst) : "v"(src) : "memory")
// L1/L2-bypassing 16B load (coherent at L3; producers drained theirs pre-barrier)
#define CLOAD(dst, src) \
    asm volatile("global_load_dwordx4 %0, %1, off sc0 sc1" : "=v"(dst) : "v"(src) : "memory")

// ---------------- setup kernels ----------------

__global__ void k_gather(const int* __restrict__ x, const float* __restrict__ emb,
                         f16* __restrict__ xe) {
    int row  = blockIdx.x * 4 + (threadIdx.x >> 6);
    int lane = threadIdx.x & 63;
    int tok  = x[row];
    const float* er = emb + (size_t)tok * E_;
    f16* xr = xe + (size_t)row * EP;
#pragma unroll
    for (int e = lane; e < EP; e += 64) {
        float v = (e < E_) ? er[e] : 0.f;
        xr[e] = (f16)v;
    }
}

__global__ void k_w1t(const float* __restrict__ w1, f16* __restrict__ w1t) {
    int n = blockIdx.x;
    int k = threadIdx.x;
    float v = (k < E_) ? w1[(size_t)k * G3 + n] : 0.f;
    w1t[(size_t)n * EP + k] = (f16)v;
}

__global__ void k_w2f(const float* __restrict__ w2, f16* __restrict__ w2f) {
    int g    = blockIdx.x * 256 + threadIdx.x;
    int lane = g & 63;
    int kt   = (g >> 6) & 31;
    int nt   = g >> 11;
    int krow = kt * 32 + (lane >> 4) * 8;
    int n    = nt * 16 + (lane & 15);
    f16* dst = w2f + ((size_t)(nt * 32 + kt) * 64 + lane) * 8;
#pragma unroll
    for (int j = 0; j < 8; ++j)
        dst[j] = (f16)w2[(size_t)(krow + j) * G3 + n];
}

// h0 fp32 -> hx[0] fp16, published at agent scope
__global__ void k_hinit(const float* __restrict__ h0, f16* __restrict__ hx) {
    int i = blockIdx.x * 256 + threadIdx.x;        // dword pairs
    f16 a = (f16)h0[2 * i], b = (f16)h0[2 * i + 1];
    unsigned lo = *(unsigned short*)&a, hi = *(unsigned short*)&b;
    __hip_atomic_store((unsigned*)hx + i, lo | (hi << 16),
                       __ATOMIC_RELAXED, __HIP_MEMORY_SCOPE_AGENT);
}

// ---------------- input projection GEMM ----------------
__global__ __launch_bounds__(256) void k_xp(const f16* __restrict__ xe,
                                            const f16* __restrict__ w1t,
                                            const float* __restrict__ bias0,
                                            f16* __restrict__ xp) {
    __shared__ __align__(16) f16 As[128 * 32];
    __shared__ __align__(16) f16 Bs[128 * 32];
    const int tid  = threadIdx.x;
    const int lane = tid & 63;
    const int w    = tid >> 6;
    const int wm   = w >> 1, wn = w & 1;
    const int n0   = blockIdx.x * 128;
    const int m0   = blockIdx.y * 128;

    f32x4 acc[4][4];
    const f32x4 z4 = {0.f, 0.f, 0.f, 0.f};
#pragma unroll
    for (int i = 0; i < 4; ++i)
#pragma unroll
        for (int j = 0; j < 4; ++j) acc[i][j] = z4;

    for (int kk = 0; kk < EP / 32; ++kk) {
        int k0 = kk * 32;
        __syncthreads();
#pragma unroll
        for (int c = 0; c < 2; ++c) {
            int t2 = tid + 256 * c;
            int row = t2 >> 2, kq = t2 & 3;
            ((half8*)As)[t2] = *(const half8*)(xe  + (size_t)(m0 + row) * EP + k0 + kq * 8);
            ((half8*)Bs)[t2] = *(const half8*)(w1t + (size_t)(n0 + row) * EP + k0 + kq * 8);
        }
        __syncthreads();
        half8 a[4], b[4];
#pragma unroll
        for (int i = 0; i < 4; ++i) {
            a[i] = ((half8*)As)[(wm * 64 + i * 16 + (lane & 15)) * 4 + (lane >> 4)];
            b[i] = ((half8*)Bs)[(wn * 64 + i * 16 + (lane & 15)) * 4 + (lane >> 4)];
        }
#pragma unroll
        for (int i = 0; i < 4; ++i)
#pragma unroll
            for (int j = 0; j < 4; ++j)
                acc[i][j] = __builtin_amdgcn_mfma_f32_16x16x32_f16(a[i], b[j], acc[i][j], 0, 0, 0);
    }

    float bv[4];
#pragma unroll
    for (int j = 0; j < 4; ++j) bv[j] = bias0[n0 + wn * 64 + j * 16 + (lane & 15)];
#pragma unroll
    for (int i = 0; i < 4; ++i)
#pragma unroll
        for (int j = 0; j < 4; ++j)
#pragma unroll
            for (int e = 0; e < 4; ++e) {
                int rl  = wm * 64 + i * 16 + (lane >> 4) * 4 + e;
                int bt  = m0 + rl;
                int tt  = bt & (T_ - 1);
                int bb  = bt >> 9;
                int col = n0 + wn * 64 + j * 16 + (lane & 15);
                xp[((size_t)tt * B_ + bb) * G3 + col] = (f16)(acc[i][j][e] + bv[j]);
            }
}

// ---------------- persistent GRU recurrence ----------------
// 128 blocks x 512 threads. rw = blk&3 (16 batch rows), ut2 = blk>>2 (32 u).
// Waves: uw = wave>>2 (u-tile), kw = wave&3 (K chunk of 256).
__global__ __launch_bounds__(512, 2) void k_rec(const f16* __restrict__ xp,
                                                const f16* __restrict__ w2f,
                                                const float* __restrict__ bias1,
                                                const float* __restrict__ h0,
                                                f16* __restrict__ hx,
                                                float* __restrict__ out,
                                                unsigned* __restrict__ ctr) {
    const int tid  = threadIdx.x;
    const int lane = tid & 63;
    const int wave = tid >> 6;          // 0..7
    const int uw   = wave >> 2;         // 0..1
    const int kw   = wave & 3;          // 0..3
    const int rw   = blockIdx.x & 3;
    const int ut2  = blockIdx.x >> 2;   // 0..31
    const int ut16 = ut2 * 2 + uw;      // 16-u tile id 0..63

    __shared__ __align__(16) f16   hs[16 * 1024];       // 32 KB staged h
    __shared__ __align__(16) float red[8][3][64][4];    // 24 KB K-partials

    // resident weights: opaque asm loads -> pinned in VGPRs (96 regs)
    half8 bw[3][8];
#pragma unroll
    for (int g = 0; g < 3; ++g) {
        int nt = g * 64 + ut16;
#pragma unroll
        for (int k8 = 0; k8 < 8; ++k8) {
            int kt = kw * 8 + k8;
            const f16* src = w2f + ((size_t)(nt * 32 + kt) * 64 + lane) * 8;
            WLOAD(bw[g][k8], src);
        }
    }
    asm volatile("s_waitcnt vmcnt(0)" ::: "memory");

    const int row  = tid >> 5;          // 0..15
    const int u32  = tid & 31;          // 0..31
    const int rowg = rw * 16 + row;     // global batch row
    const int ug   = ut2 * 32 + u32;    // hidden unit
    float h = h0[rowg * U_ + ug];       // fp32 state in register
    const float bz = bias1[ug], br = bias1[U_ + ug], bh = bias1[2 * U_ + ug];
    const int lsrc = (row >> 2) * 16 + (u32 & 15);
    const int ei   = row & 3;
    const int uwq  = u32 >> 4;
    const f32x4 z4 = {0.f, 0.f, 0.f, 0.f};
    unsigned* myctr = ctr + rw * 2048;  // per-group private counter page

    // stage geometry: thread moves 4x16B blocks, LDS index == global index
    const f16* gsb = hx + (size_t)rowg * U_ + (size_t)u32 * 8; // +32*8*i halves
    half8* ldsrow  = (half8*)(hs + row * 1024);                 // 16B blocks
    const f16* hrow = hs + (lane & 15) * 1024 + kw * 256 + (lane >> 4) * 8;
    float* outrow = out + (size_t)rowg * T_ * U_ + ug;

    // xp prefetch for t=0
    const f16* xpb = xp + (size_t)rowg * G3 + ug;
    float xz = (float)xpb[0], xr = (float)xpb[(size_t)U_], xh = (float)xpb[(size_t)2 * U_];

#pragma unroll 1
    for (int t = 0; t < T_; ++t) {
        // ---- 1. stage hx[t&1] -> LDS (L1/L2-bypass loads, issued at release) ----
        const f16* gs = gsb + (size_t)(t & 1) * (B_ * U_);
        half8 v0, v1, v2, v3;
        CLOAD(v0, gs);
        CLOAD(v1, gs + 256);
        CLOAD(v2, gs + 512);
        CLOAD(v3, gs + 768);
        asm volatile("s_waitcnt vmcnt(0)" ::: "memory");
        ldsrow[u32]      = v0;
        ldsrow[u32 + 32] = v1;
        ldsrow[u32 + 64] = v2;
        ldsrow[u32 + 96] = v3;
        // out store for h_{t-1}: off the critical path (drains ~2000cy later)
        if (t) outrow[(size_t)(t - 1) * U_] = h;
        barrier_lds();

        // ---- 2. A fragments from LDS (16-lane broadcast reads) ----
        half8 af[8];
#pragma unroll
        for (int k8 = 0; k8 < 8; ++k8)
            af[k8] = *(const half8*)(hrow + k8 * 32);

        // ---- 3. prefetch xp for t+1 ----
        int tn = (t < T_ - 1) ? t + 1 : t;
        const f16* xpn = xp + ((size_t)tn * B_ + rowg) * G3 + ug;
        float xzn = (float)xpn[0], xrn = (float)xpn[(size_t)U_], xhn = (float)xpn[(size_t)2 * U_];

        // ---- 4. MFMA ----
        f32x4 acc[3] = {z4, z4, z4};
#pragma unroll
        for (int k8 = 0; k8 < 8; ++k8)
#pragma unroll
            for (int g = 0; g < 3; ++g)
                acc[g] = __builtin_amdgcn_mfma_f32_16x16x32_f16(af[k8], bw[g][k8], acc[g], 0, 0, 0);

        // ---- 5. K-reduce via LDS ----
#pragma unroll
        for (int g = 0; g < 3; ++g)
            *(f32x4*)&red[wave][g][lane][0] = acc[g];
        barrier_lds();

        float sz = 0.f, sr = 0.f, sh = 0.f;
#pragma unroll
        for (int k2 = 0; k2 < 4; ++k2) {
            int w2 = uwq * 4 + k2;
            sz += red[w2][0][lsrc][ei];
            sr += red[w2][1][lsrc][ei];
            sh += red[w2][2][lsrc][ei];
        }

        // ---- 6. epilogue ----
        float zg = 1.f / (1.f + expf(-(xz + sz + bz)));
        float rg = 1.f / (1.f + expf(-(xr + sr + br)));
        float hh = tanhf(xh + rg * (sh + bh));
        h = zg * h + (1.f - zg) * hh;

        // publish h_t (fp16 pair, write-through to coherent point)
        f16 hf = (f16)h;
        unsigned my = *(unsigned short*)&hf;
        unsigned nb = __shfl_down(my, 1);
        if ((u32 & 1) == 0) {
            unsigned* dst = (unsigned*)(hx + (size_t)((t + 1) & 1) * (B_ * U_)
                                        + (size_t)rowg * U_ + ug);
            __hip_atomic_store(dst, my | (nb << 16),
                               __ATOMIC_RELAXED, __HIP_MEMORY_SCOPE_AGENT);
        }

        // ---- 7. group barrier (drains hx store; out store already done) ----
        __syncthreads();
        if (tid == 0) {
            __hip_atomic_fetch_add(myctr + t, 1u,
                                   __ATOMIC_RELAXED, __HIP_MEMORY_SCOPE_AGENT);
            while (__hip_atomic_load(myctr + t,
                                     __ATOMIC_RELAXED, __HIP_MEMORY_SCOPE_AGENT) < 32u)
                __builtin_amdgcn_s_sleep(1);
        }
        __syncthreads();

        xz = xzn; xr = xrn; xh = xhn;
    }
    outrow[(size_t)(T_ - 1) * U_] = h;
    out[(size_t)B_ * T_ * U_ + (size_t)rowg * U_ + ug] = h;
}

// ---------------- host ----------------
extern "C" void kernel_launch(void* const* d_in, const int* in_sizes, int n_in,
                              void* d_out, int out_size, void* d_ws, size_t ws_size,
                              hipStream_t stream) {
    const int*   x    = (const int*)d_in[0];
    const float* h0   = (const float*)d_in[1];
    const float* emb  = (const float*)d_in[2];
    const float* w1   = (const float*)d_in[3];
    const float* w2   = (const float*)d_in[4];
    const float* bias = (const float*)d_in[5];
    float* out = (float*)d_out;
    char*  ws  = (char*)d_ws;

    f16*      xe   = (f16*)(ws + OFF_XE);
    f16*      w1t  = (f16*)(ws + OFF_W1T);
    f16*      w2f  = (f16*)(ws + OFF_W2F);
    f16*      xp   = (f16*)(ws + OFF_XP);
    f16*      hx   = (f16*)(ws + OFF_HX);     // time-shared with xe
    unsigned* ctr  = (unsigned*)(ws + OFF_CTR2);

    k_gather<<<B_ * T_ / 4, 256, 0, stream>>>(x, emb, xe);
    k_w1t<<<G3, EP, 0, stream>>>(w1, w1t);
    k_w2f<<<(192 * 32 * 64) / 256, 256, 0, stream>>>(w2, w2f);
    k_xp<<<dim3(G3 / 128, B_ * T_ / 128), 256, 0, stream>>>(xe, w1t, bias, xp);

    // xe region is dead now; hx/ctr live inside it
    hipMemsetAsync(ctr, 0, 4 * 2048 * sizeof(unsigned), stream);
    k_hinit<<<(B_ * U_ / 2) / 256, 256, 0, stream>>>(h0, hx);

    const f16*   xp_c   = xp;
    const f16*   w2f_c  = w2f;
    const float* bias1  = bias + G3;
    void* args[] = {(void*)&xp_c, (void*)&w2f_c, (void*)&bias1, (void*)&h0,
                    (void*)&hx, (void*)&out, (void*)&ctr};
    if (hipLaunchCooperativeKernel((const void*)k_rec, dim3(128), dim3(512),
                                   args, 0, stream) != hipSuccess) {
        k_rec<<<128, 512, 0, stream>>>(xp_c, w2f_c, bias1, h0, hx, out, ctr);
    }
}